// Round 13
// baseline (102.969 us; speedup 1.0000x reference)
//
#include <hip/hip_runtime.h>
#include <hip/hip_bf16.h>

#define NROWS 12288
#define DDIM  128
#define NT    96      // 12288/128 tiles per dimension
#define NTILE 4656    // NT*(NT+1)/2 upper-tri tiles
#define NBLK  512     // exactly 2 blocks/CU, single round, uniform 9-10 tiles/block
#define MAXT  10

typedef __bf16 bf16x8 __attribute__((ext_vector_type(8)));
typedef float  f32x4  __attribute__((ext_vector_type(4)));

// async global->LDS, 16B per lane; LDS dst is wave-uniform base + lane*16
#define GLD_LDS(g, l) __builtin_amdgcn_global_load_lds(                      \
    (const __attribute__((address_space(1))) void*)(g),                      \
    (__attribute__((address_space(3))) void*)(l), 16, 0, 0)

__device__ __forceinline__ unsigned short f2bf(float f) {
    union { float f; unsigned u; } a; a.f = f;
    unsigned r = a.u + 0x7fffu + ((a.u >> 16) & 1u);   // RNE to bf16
    return (unsigned short)(r >> 16);
}

// Convert f32 -> bf16 AND permute into fragment-major layout:
// for 16-row block rb, k-chunk ks (16B units c = ks*4+q), lane l = m16 + 16q:
//   xbT ushort offset ((rb*4 + ks)*64 + l) * 8  holds row rb*16+m16, bytes [c*16, c*16+16)
// so every MFMA fragment load is ONE fully-coalesced 1KB global_load_dwordx4,
// and one band's A (128 rows) is a CONTIGUOUS 32KB region (bi*32KB).
__global__ void convert_kernel(const float* __restrict__ x, unsigned short* __restrict__ xbT,
                               float* __restrict__ rowsum, float* __restrict__ out) {
    int gid = blockIdx.x * 256 + threadIdx.x;    // 196608 threads, one 16B chunk each
    int e = gid << 3;
    float4 v0 = *(const float4*)(x + e);
    float4 v1 = *(const float4*)(x + e + 4);
    uint4 o;
    o.x = (unsigned)f2bf(v0.x) | ((unsigned)f2bf(v0.y) << 16);
    o.y = (unsigned)f2bf(v0.z) | ((unsigned)f2bf(v0.w) << 16);
    o.z = (unsigned)f2bf(v1.x) | ((unsigned)f2bf(v1.y) << 16);
    o.w = (unsigned)f2bf(v1.z) | ((unsigned)f2bf(v1.w) << 16);
    int r = gid >> 4;          // row
    int c = gid & 15;          // 16B chunk within row
    int off = (((r >> 4) * 4 + (c >> 2)) * 64 + (c & 3) * 16 + (r & 15)) * 8;
    *(uint4*)(xbT + off) = o;
    if (gid < NROWS) rowsum[gid] = 0.f;
    if (gid == 0) out[0] = 0.f;
}

// Software-pipelined barrier-free GEMM+exp+rowsum over band-major tile list.
// Block b owns tiles [b*4656/512, (b+1)*4656/512). A of the current band lives
// in LDS (staged once per band, re-read per ks as ds_read_b128); B fragments
// ping-pong between two register sets, and tile t+1's 16 global loads are
// ISSUED BEFORE tile t's MFMA+epilogue so ~1300 cyc of compute hides L2 latency.
// NOTE: register cap: do NOT raise launch_bounds to 4 (R9: spill catastrophe).
__global__ __launch_bounds__(256, 2) void gemm_exp_rowsum(
    const unsigned short* __restrict__ xbT, float* __restrict__ rowsum)
{
    __shared__ __align__(16) unsigned short Alds[128 * DDIM];  // 32KB frag-major A band
    __shared__ float csumS[MAXT * 128];          // 5 KB strip-local col partials
    __shared__ int jtArr[MAXT];

    const int tid = threadIdx.x;
    const int g0 = (blockIdx.x * NTILE) >> 9;
    const int g1 = ((blockIdx.x + 1) * NTILE) >> 9;
    const int nt = g1 - g0;                      // 9 or 10

    // decode g0 -> (band bi, tile col jt)
    int bi = 0, rem = g0;
    while (rem >= NT - bi) { rem -= NT - bi; ++bi; }
    int jt = bi + rem;
    const int bi0 = bi, jt0 = jt;

    for (int k = tid; k < MAXT * 128; k += 256) csumS[k] = 0.f;

    const int wave = tid >> 6, lane = tid & 63;
    const int m16 = lane & 15, q = lane >> 4;
    const int wr = wave >> 1, wc = wave & 1;     // 2x2 waves, 64x64 quadrants

    // stage current band's A (contiguous 32KB at xbT + bi*16384) into LDS
    #define STAGE_A() do {                                                       \
        _Pragma("unroll")                                                        \
        for (int r8 = 0; r8 < 8; ++r8) {                                         \
            int ch = r8 * 256 + wave * 64;       /* wave-uniform 16B-chunk base */\
            GLD_LDS(xbT + bi * 16384 + (ch + lane) * 8, Alds + ch * 8);          \
        }                                                                        \
    } while (0)

    STAGE_A();
    __syncthreads();   // A staged (vmcnt drained) + csumS zeroed

    // exp(s/T) == exp2(s * invT*log2e)
    const float SCALE = 20.609929155556625f;     // (1/0.07) * log2(e)

    f32x4 rp4[4];
    #pragma unroll
    for (int mi = 0; mi < 4; ++mi) rp4[mi] = (f32x4){0.f, 0.f, 0.f, 0.f};

    #define FLUSH_RP() do {                                                      \
        _Pragma("unroll")                                                        \
        for (int mi = 0; mi < 4; ++mi) {                                         \
            _Pragma("unroll")                                                    \
            for (int r = 0; r < 4; ++r) {                                        \
                float s = rp4[mi][r];                                            \
                s += __shfl_xor(s, 1);                                           \
                s += __shfl_xor(s, 2);                                           \
                s += __shfl_xor(s, 4);                                           \
                s += __shfl_xor(s, 8);                                           \
                if (m16 == 0)                                                    \
                    atomicAdd(&rowsum[bi * 128 + wr * 64 + mi * 16 + q * 4 + r], s); \
            }                                                                    \
            rp4[mi] = (f32x4){0.f, 0.f, 0.f, 0.f};                               \
        }                                                                        \
    } while (0)

    // issue 16 coalesced 1KB loads of tile jtv's B quadrant into dst regs
    #define LOAD_B(dst, jtv) do {                                                \
        int bb = ((jtv) * 8 + wc * 4) * 4;                                       \
        _Pragma("unroll")                                                        \
        for (int ni = 0; ni < 4; ++ni)                                           \
            _Pragma("unroll")                                                    \
            for (int ks = 0; ks < 4; ++ks)                                       \
                dst[ks][ni] = *(const bf16x8*)(xbT + ((bb + ni * 4 + ks) * 64 + lane) * 8); \
    } while (0)

    // MFMA + exp + partials for current tile (af streamed per-ks from LDS)
    #define COMPUTE(bfr, t) do {                                                 \
        f32x4 acc[4][4] = {};                                                    \
        _Pragma("unroll")                                                        \
        for (int ks = 0; ks < 4; ++ks) {                                         \
            bf16x8 afk[4];                                                       \
            _Pragma("unroll")                                                    \
            for (int mi = 0; mi < 4; ++mi)                                       \
                afk[mi] = *(const bf16x8*)(&Alds[(((wr * 4 + mi) * 4 + ks) * 64 + lane) * 8]); \
            _Pragma("unroll")                                                    \
            for (int mi = 0; mi < 4; ++mi)                                       \
                _Pragma("unroll")                                                \
                for (int ni = 0; ni < 4; ++ni)                                   \
                    acc[mi][ni] = __builtin_amdgcn_mfma_f32_16x16x32_bf16(       \
                        afk[mi], bfr[ks][ni], acc[mi][ni], 0, 0, 0);             \
        }                                                                        \
        f32x4 cp4[4];                                                            \
        _Pragma("unroll")                                                        \
        for (int ni = 0; ni < 4; ++ni) cp4[ni] = (f32x4){0.f, 0.f, 0.f, 0.f};    \
        _Pragma("unroll")                                                        \
        for (int mi = 0; mi < 4; ++mi)                                           \
            _Pragma("unroll")                                                    \
            for (int ni = 0; ni < 4; ++ni) {                                     \
                f32x4 sv = acc[mi][ni] * SCALE;                                  \
                f32x4 ev;                                                        \
                ev[0] = __builtin_amdgcn_exp2f(sv[0]);                           \
                ev[1] = __builtin_amdgcn_exp2f(sv[1]);                           \
                ev[2] = __builtin_amdgcn_exp2f(sv[2]);                           \
                ev[3] = __builtin_amdgcn_exp2f(sv[3]);                           \
                rp4[mi] += ev;                                                   \
                cp4[ni] += ev;                                                   \
            }                                                                    \
        if (jt != bi) {                                                          \
            _Pragma("unroll")                                                    \
            for (int ni = 0; ni < 4; ++ni) {                                     \
                float s = (cp4[ni][0] + cp4[ni][1]) + (cp4[ni][2] + cp4[ni][3]); \
                s += __shfl_xor(s, 16);                                          \
                s += __shfl_xor(s, 32);                                          \
                if (q == 0) atomicAdd(&csumS[(t) * 128 + wc * 64 + ni * 16 + m16], s); \
            }                                                                    \
        }                                                                        \
    } while (0)

    // advance (jt,bi); on band switch: flush row partials, restage A (uniform)
    #define POST(jn, bn, more) do {                                              \
        if ((more) && (bn) != bi) {                                              \
            FLUSH_RP();                                                          \
            bi = (bn);                                                           \
            __syncthreads();        /* all waves done reading Alds */            \
            STAGE_A();                                                           \
            __syncthreads();        /* restage complete (vmcnt drained) */       \
        } else {                                                                 \
            bi = (bn);                                                           \
        }                                                                        \
        jt = (jn);                                                               \
    } while (0)

    bf16x8 bA[4][4], bB[4][4];
    LOAD_B(bA, jt);
    int t = 0;
    for (;;) {
        {   // phase A: compute bA, prefetch into bB
            int jn = jt + 1, bn = bi;
            if (jn == NT) { bn = bi + 1; jn = bn; }
            bool more = (t + 1 < nt);
            if (more) LOAD_B(bB, jn);            // issued BEFORE compute: latency hidden
            COMPUTE(bA, t);
            if (!more) break;
            POST(jn, bn, more);
            ++t;
        }
        {   // phase B: compute bB, prefetch into bA
            int jn = jt + 1, bn = bi;
            if (jn == NT) { bn = bi + 1; jn = bn; }
            bool more = (t + 1 < nt);
            if (more) LOAD_B(bA, jn);
            COMPUTE(bB, t);
            if (!more) break;
            POST(jn, bn, more);
            ++t;
        }
    }
    FLUSH_RP();

    // writeout col partials: jt per strip slot t
    if (tid == 0) {
        int bb = bi0, jj = jt0;
        for (int tt = 0; tt < nt; ++tt) {
            jtArr[tt] = jj;
            ++jj; if (jj == NT) { ++bb; jj = bb; }
        }
    }
    __syncthreads();   // csumS atomics + jtArr visible
    for (int k = tid; k < nt * 128; k += 256) {
        float v = csumS[k];
        if (v != 0.f) atomicAdd(&rowsum[jtArr[k >> 7] * 128 + (k & 127)], v);
    }
    #undef STAGE_A
    #undef FLUSH_RP
    #undef LOAD_B
    #undef COMPUTE
    #undef POST
}

__global__ void finalize_kernel(const float* __restrict__ rowsum, float* __restrict__ out) {
    __shared__ float red[4];
    int gid = blockIdx.x * 256 + threadIdx.x;
    float lg = __logf(rowsum[gid]);
    #pragma unroll
    for (int off = 1; off < 64; off <<= 1)
        lg += __shfl_xor(lg, off);
    const int wv = threadIdx.x >> 6, ln = threadIdx.x & 63;
    if (ln == 0) red[wv] = lg;
    __syncthreads();
    if (threadIdx.x == 0)
        atomicAdd(out, (red[0] + red[1] + red[2] + red[3]) * (1.0f / (float)NROWS));
}

extern "C" void kernel_launch(void* const* d_in, const int* in_sizes, int n_in,
                              void* d_out, int out_size, void* d_ws, size_t ws_size,
                              hipStream_t stream) {
    const float* x = (const float*)d_in[0];
    float* out = (float*)d_out;

    float* rowsum = (float*)d_ws;                                                  // 48 KB
    unsigned short* xbT = (unsigned short*)((char*)d_ws + NROWS * sizeof(float));  // 3 MB bf16, frag-major

    convert_kernel<<<dim3((NROWS * DDIM) / (8 * 256)), dim3(256), 0, stream>>>(x, xbT, rowsum, out);
    gemm_exp_rowsum<<<dim3(NBLK), dim3(256), 0, stream>>>(xbT, rowsum);
    finalize_kernel<<<dim3(NROWS / 256), dim3(256), 0, stream>>>(rowsum, out);
}

// Round 14
// 96.509 us; speedup vs baseline: 1.0669x; 1.0669x over previous
//
#include <hip/hip_runtime.h>
#include <hip/hip_bf16.h>

#define NROWS 12288
#define DDIM  128
#define NT    96      // 12288/128 tiles per dimension
#define NTILE 4656    // NT*(NT+1)/2 upper-tri tiles
#define NBLK  768     // exactly 3 blocks/CU, single round, 6-7 tiles/block
#define MAXT  7

typedef __bf16 bf16x8 __attribute__((ext_vector_type(8)));
typedef float  f32x4  __attribute__((ext_vector_type(4)));

// async global->LDS, 16B per lane; LDS dst is wave-uniform base + lane*16
#define GLD_LDS(g, l) __builtin_amdgcn_global_load_lds(                      \
    (const __attribute__((address_space(1))) void*)(g),                      \
    (__attribute__((address_space(3))) void*)(l), 16, 0, 0)

__device__ __forceinline__ unsigned short f2bf(float f) {
    union { float f; unsigned u; } a; a.f = f;
    unsigned r = a.u + 0x7fffu + ((a.u >> 16) & 1u);   // RNE to bf16
    return (unsigned short)(r >> 16);
}

// Convert f32 -> bf16 AND permute into fragment-major layout:
// for 16-row block rb, k-chunk ks (16B units c = ks*4+q), lane l = m16 + 16q:
//   xbT ushort offset ((rb*4 + ks)*64 + l) * 8  holds row rb*16+m16, bytes [c*16, c*16+16)
// -> every MFMA fragment load is ONE coalesced 1KB global_load_dwordx4, and one
// band's A (128 rows) is a CONTIGUOUS 32KB region (bi*32KB).
__global__ void convert_kernel(const float* __restrict__ x, unsigned short* __restrict__ xbT,
                               float* __restrict__ rowsum, float* __restrict__ out) {
    int gid = blockIdx.x * 256 + threadIdx.x;    // 196608 threads, one 16B chunk each
    int e = gid << 3;
    float4 v0 = *(const float4*)(x + e);
    float4 v1 = *(const float4*)(x + e + 4);
    uint4 o;
    o.x = (unsigned)f2bf(v0.x) | ((unsigned)f2bf(v0.y) << 16);
    o.y = (unsigned)f2bf(v0.z) | ((unsigned)f2bf(v0.w) << 16);
    o.z = (unsigned)f2bf(v1.x) | ((unsigned)f2bf(v1.y) << 16);
    o.w = (unsigned)f2bf(v1.z) | ((unsigned)f2bf(v1.w) << 16);
    int r = gid >> 4;          // row
    int c = gid & 15;          // 16B chunk within row
    int off = (((r >> 4) * 4 + (c >> 2)) * 64 + (c & 3) * 16 + (r & 15)) * 8;
    *(uint4*)(xbT + off) = o;
    if (gid < NROWS) rowsum[gid] = 0.f;
    if (gid == 0) out[0] = 0.f;
}

// Low-register barrier-free GEMM+exp+rowsum: A per-ks from LDS (16 live regs),
// B per-ks double-buffered (32 live), acc 64 AGPR -> ~145 regs total, fits
// 3 waves/SIMD (grid 768 = 3 blocks/CU co-resident). ks+1's 4 loads issue
// before ks's 16 MFMAs; next tile's ks0 issues before the exp epilogue.
// NOTE: do NOT force 4 blocks/CU (R9/R13: VGPR<=128 -> scratch spill).
__global__ __launch_bounds__(256, 3) void gemm_exp_rowsum(
    const unsigned short* __restrict__ xbT, float* __restrict__ rowsum)
{
    __shared__ __align__(16) unsigned short Alds[128 * DDIM];  // 32KB frag-major A band
    __shared__ float csumS[MAXT * 128];          // 3.5 KB strip-local col partials
    __shared__ int jtArr[MAXT];

    const int tid = threadIdx.x;
    const int g0 = (blockIdx.x * NTILE) / NBLK;
    const int g1 = ((blockIdx.x + 1) * NTILE) / NBLK;
    const int nt = g1 - g0;                      // 6 or 7

    // decode g0 -> (band bi, tile col jt)
    int bi = 0, rem = g0;
    while (rem >= NT - bi) { rem -= NT - bi; ++bi; }
    int jt = bi + rem;
    const int bi0 = bi, jt0 = jt;

    for (int k = tid; k < MAXT * 128; k += 256) csumS[k] = 0.f;

    const int wave = tid >> 6, lane = tid & 63;
    const int m16 = lane & 15, q = lane >> 4;
    const int wr = wave >> 1, wc = wave & 1;     // 2x2 waves, 64x64 quadrants

    // stage current band's A (contiguous 32KB at xbT + bi*16384) into LDS
    #define STAGE_A() do {                                                       \
        _Pragma("unroll")                                                        \
        for (int r8 = 0; r8 < 8; ++r8) {                                         \
            int ch = r8 * 256 + wave * 64;       /* wave-uniform 16B-chunk base */\
            GLD_LDS(xbT + bi * 16384 + (ch + lane) * 8, Alds + ch * 8);          \
        }                                                                        \
    } while (0)

    STAGE_A();
    __syncthreads();   // A staged (vmcnt drained) + csumS zeroed

    // exp(s/T) == exp2(s * invT*log2e)
    const float SCALE = 20.609929155556625f;     // (1/0.07) * log2(e)

    f32x4 rp4[4];
    #pragma unroll
    for (int mi = 0; mi < 4; ++mi) rp4[mi] = (f32x4){0.f, 0.f, 0.f, 0.f};

    #define FLUSH_RP() do {                                                      \
        _Pragma("unroll")                                                        \
        for (int mi = 0; mi < 4; ++mi) {                                         \
            _Pragma("unroll")                                                    \
            for (int r = 0; r < 4; ++r) {                                        \
                float s = rp4[mi][r];                                            \
                s += __shfl_xor(s, 1);                                           \
                s += __shfl_xor(s, 2);                                           \
                s += __shfl_xor(s, 4);                                           \
                s += __shfl_xor(s, 8);                                           \
                if (m16 == 0)                                                    \
                    atomicAdd(&rowsum[bi * 128 + wr * 64 + mi * 16 + q * 4 + r], s); \
            }                                                                    \
            rp4[mi] = (f32x4){0.f, 0.f, 0.f, 0.f};                               \
        }                                                                        \
    } while (0)

    // 4 coalesced 1KB loads: tile jtv's B quadrant, k-chunk ks only
    #define LOAD_BKS(dst, jtv, ks) do {                                          \
        int bb = ((jtv) * 8 + wc * 4);                                           \
        _Pragma("unroll")                                                        \
        for (int ni = 0; ni < 4; ++ni)                                           \
            dst[ni] = *(const bf16x8*)(xbT + (((bb + ni) * 4 + (ks)) * 64 + lane) * 8); \
    } while (0)

    // 4 ds_read_b128 (A frags, conflict-free) + 16 MFMA for one ks
    #define MFMA_KS(ks, bfr) do {                                                \
        bf16x8 afk[4];                                                           \
        _Pragma("unroll")                                                        \
        for (int mi = 0; mi < 4; ++mi)                                           \
            afk[mi] = *(const bf16x8*)(&Alds[(((wr * 4 + mi) * 4 + (ks)) * 64 + lane) * 8]); \
        _Pragma("unroll")                                                        \
        for (int mi = 0; mi < 4; ++mi)                                           \
            _Pragma("unroll")                                                    \
            for (int ni = 0; ni < 4; ++ni)                                       \
                acc[mi][ni] = __builtin_amdgcn_mfma_f32_16x16x32_bf16(           \
                    afk[mi], bfr[ni], acc[mi][ni], 0, 0, 0);                     \
    } while (0)

    bf16x8 bf0[4], bf1[4];
    LOAD_BKS(bf0, jt, 0);

    for (int t = 0; t < nt; ++t) {
        int jn = jt + 1, bn = bi;
        if (jn == NT) { bn = bi + 1; jn = bn; }
        const bool more = (t + 1 < nt);

        f32x4 acc[4][4] = {};
        LOAD_BKS(bf1, jt, 1);
        MFMA_KS(0, bf0);
        LOAD_BKS(bf0, jt, 2);
        MFMA_KS(1, bf1);
        LOAD_BKS(bf1, jt, 3);
        MFMA_KS(2, bf0);
        if (more) LOAD_BKS(bf0, jn, 0);          // next tile's ks0: hidden under ks3+epilogue
        MFMA_KS(3, bf1);

        // C/D layout: col = m16, row = q*4 + r  [verified, absmax=0]
        f32x4 cp4[4];
        #pragma unroll
        for (int ni = 0; ni < 4; ++ni) cp4[ni] = (f32x4){0.f, 0.f, 0.f, 0.f};

        #pragma unroll
        for (int mi = 0; mi < 4; ++mi)
            #pragma unroll
            for (int ni = 0; ni < 4; ++ni) {
                f32x4 sv = acc[mi][ni] * SCALE;
                f32x4 ev;
                ev[0] = __builtin_amdgcn_exp2f(sv[0]);
                ev[1] = __builtin_amdgcn_exp2f(sv[1]);
                ev[2] = __builtin_amdgcn_exp2f(sv[2]);
                ev[3] = __builtin_amdgcn_exp2f(sv[3]);
                rp4[mi] += ev;                   // row partials (register, per band)
                cp4[ni] += ev;                   // col partials (this tile)
            }

        if (jt != bi) {                          // diagonal tile: rows only, no double count
            #pragma unroll
            for (int ni = 0; ni < 4; ++ni) {
                float s = (cp4[ni][0] + cp4[ni][1]) + (cp4[ni][2] + cp4[ni][3]);
                s += __shfl_xor(s, 16);
                s += __shfl_xor(s, 32);
                if (q == 0) atomicAdd(&csumS[t * 128 + wc * 64 + ni * 16 + m16], s);
            }
        }

        if (more && bn != bi) {                  // band switch (block-uniform, rare)
            FLUSH_RP();
            bi = bn;
            __syncthreads();                     // all waves done reading Alds
            STAGE_A();
            __syncthreads();                     // restage complete
        }
        jt = jn;
    }
    FLUSH_RP();

    // writeout col partials: jt per strip slot t
    if (tid == 0) {
        int bb = bi0, jj = jt0;
        for (int tt = 0; tt < nt; ++tt) {
            jtArr[tt] = jj;
            ++jj; if (jj == NT) { ++bb; jj = bb; }
        }
    }
    __syncthreads();   // csumS atomics + jtArr visible
    for (int k = tid; k < nt * 128; k += 256) {
        float v = csumS[k];
        if (v != 0.f) atomicAdd(&rowsum[jtArr[k >> 7] * 128 + (k & 127)], v);
    }
    #undef STAGE_A
    #undef FLUSH_RP
    #undef LOAD_BKS
    #undef MFMA_KS
}

__global__ void finalize_kernel(const float* __restrict__ rowsum, float* __restrict__ out) {
    __shared__ float red[4];
    int gid = blockIdx.x * 256 + threadIdx.x;
    float lg = __logf(rowsum[gid]);
    #pragma unroll
    for (int off = 1; off < 64; off <<= 1)
        lg += __shfl_xor(lg, off);
    const int wv = threadIdx.x >> 6, ln = threadIdx.x & 63;
    if (ln == 0) red[wv] = lg;
    __syncthreads();
    if (threadIdx.x == 0)
        atomicAdd(out, (red[0] + red[1] + red[2] + red[3]) * (1.0f / (float)NROWS));
}

extern "C" void kernel_launch(void* const* d_in, const int* in_sizes, int n_in,
                              void* d_out, int out_size, void* d_ws, size_t ws_size,
                              hipStream_t stream) {
    const float* x = (const float*)d_in[0];
    float* out = (float*)d_out;

    float* rowsum = (float*)d_ws;                                                  // 48 KB
    unsigned short* xbT = (unsigned short*)((char*)d_ws + NROWS * sizeof(float));  // 3 MB bf16, frag-major

    convert_kernel<<<dim3((NROWS * DDIM) / (8 * 256)), dim3(256), 0, stream>>>(x, xbT, rowsum, out);
    gemm_exp_rowsum<<<dim3(NBLK), dim3(256), 0, stream>>>(xbT, rowsum);
    finalize_kernel<<<dim3(NROWS / 256), dim3(256), 0, stream>>>(rowsum, out);
}